// Round 12
// baseline (11663.237 us; speedup 1.0000x reference)
//
#include <hip/hip_runtime.h>

// LSTM 2-layer, S=512 B=64 IN=H=1024, fp32 I/O, fp16 MFMA compute.
// R12 = R11 with:
//  (1) comms wave wv4 (320 thr/wg): wg0/wv4 aggregates BOTH epoch chains in a
//      dedicated loop (never barriers, s_sleep polls); wg!=0 wv4 exits.
//      Consumers poll the 32 global epoch replicas directly (no LDS mirror).
//      -> aggregation is fully OFF the compute critical path (R9/R11 flaw).
//  (2) compute barrier = 4-wave LDS counter with s_sleep(1) spin (R10's hot
//      spin fixed); __syncthreads impossible with a non-barriering wv4.
//  (3) frag-ordered weight LDS layout: chunk(wv,kk,lane) at lane*16+kk*1024
//      -> every weight ds_read_b128 is 64x consecutive 16B = conflict-free
//      (old XOR layout was 8-way conflicted: q*16 aliased (r&7)<<4).
// Unchanged: two-phase round, split epoch chains, sc0|sc1 h rings, relaxed
// flags, no fences in loop, h0ring may alias d_out upper half (out[511]
// deferred past epoch1>=SEQ).

#define SEQ   512
#define BATCH 64
#define HID   1024
#define NG    4096
#define KCAT  2048
#define F0_BASE 0            // flags0: + wg*32
#define E0_IDX  8192         // epoch0 replicas: + (wg&31)*32
#define F1_BASE 16384        // flags1: + wg*32
#define E1_IDX  24576        // epoch1 replicas: + (wg&31)*32

// dynamic LDS layout (bytes):
//   [0,32768)       Wh0 frag-ordered: (wvh,kk,lane) -> wvh*16384+kk*1024+lane*16
//   [32768,98304)   W1  frag-ordered: (wv,kk,lane)  -> wv*16384+kk*1024+lane*16
//   [98304,133120)  accL: float[2][4][64][17]
//   [133120,133124) barCnt
#define SMEM_BYTES 133184

typedef __attribute__((ext_vector_type(8))) _Float16 f16x8;
typedef __attribute__((ext_vector_type(4))) _Float16 f16x4;
typedef __attribute__((ext_vector_type(4))) float    f32x4;

__device__ __forceinline__ float sigm_f(float x){ return 1.f/(1.f + __expf(-x)); }
__device__ __forceinline__ float tanh_f(float x){
    float e = __expf(-2.f*fabsf(x));
    float r = (1.f - e)/(1.f + e);
    return copysignf(r, x);
}

__device__ __forceinline__ void store_h8(_Float16* p, f16x4 v){
    asm volatile("global_store_dwordx2 %0, %1, off sc0 sc1" :: "v"(p), "v"(v) : "memory");
}
__device__ __forceinline__ void drain_vmem(){
    asm volatile("s_waitcnt vmcnt(0)" ::: "memory");
}

// ---------------- prep kernels ----------------

__global__ void prep_w_kernel(const float* __restrict__ Wx, const float* __restrict__ Wh,
                              const float* __restrict__ bx, const float* __restrict__ bh,
                              _Float16* __restrict__ Wr, float* __restrict__ br){
    int p = blockIdx.x;
    int j = p >> 2, g = p & 3;
    int r = g*1024 + j;
    int k = threadIdx.x * 8;
    const float* s = (k < 1024) ? (Wx + (size_t)r*1024 + k)
                                : (Wh + (size_t)r*1024 + (k - 1024));
    float4 v0 = *reinterpret_cast<const float4*>(s);
    float4 v1 = *reinterpret_cast<const float4*>(s + 4);
    f16x8 o;
    o[0]=(_Float16)v0.x; o[1]=(_Float16)v0.y; o[2]=(_Float16)v0.z; o[3]=(_Float16)v0.w;
    o[4]=(_Float16)v1.x; o[5]=(_Float16)v1.y; o[6]=(_Float16)v1.z; o[7]=(_Float16)v1.w;
    *reinterpret_cast<f16x8*>(Wr + (size_t)p*KCAT + k) = o;
    if (threadIdx.x == 0) br[p] = bx[r] + bh[r];
}

__global__ void prep_x_kernel(const float* __restrict__ x, _Float16* xo){
    size_t i = ((size_t)blockIdx.x*256 + threadIdx.x) * 8;
    float4 v0 = *reinterpret_cast<const float4*>(x + i);
    float4 v1 = *reinterpret_cast<const float4*>(x + i + 4);
    f16x8 o;
    o[0]=(_Float16)v0.x; o[1]=(_Float16)v0.y; o[2]=(_Float16)v0.z; o[3]=(_Float16)v0.w;
    o[4]=(_Float16)v1.x; o[5]=(_Float16)v1.y; o[6]=(_Float16)v1.z; o[7]=(_Float16)v1.w;
    *reinterpret_cast<f16x8*>(xo + i) = o;
}

__global__ void init_misc_kernel(int* flags, _Float16* hz){
    int i = blockIdx.x*256 + threadIdx.x;            // 32768 threads
    flags[i] = 0;
    if (i < 16384){
        f16x4 z; z[0]=(_Float16)0.f; z[1]=(_Float16)0.f; z[2]=(_Float16)0.f; z[3]=(_Float16)0.f;
        *reinterpret_cast<f16x4*>(hz + (size_t)i*4) = z;
    }
}

// ---------------- sync helpers (no fences) ----------------

__device__ __forceinline__ int gload(const int* p){
    return __hip_atomic_load(p, __ATOMIC_RELAXED, __HIP_MEMORY_SCOPE_AGENT);
}
__device__ __forceinline__ void gstore(int* p, int v){
    __hip_atomic_store(p, v, __ATOMIC_RELAXED, __HIP_MEMORY_SCOPE_AGENT);
}

__device__ __forceinline__ void wait_epoch_g(const int* flags, int eidx, int k, int rep){
    for(;;){
        int e = gload(&flags[eidx + rep*32]);
        if (e >= k) break;
        __builtin_amdgcn_s_sleep(2);
    }
    asm volatile("" ::: "memory");
}

__device__ __forceinline__ int wave_min(int v){
    #pragma unroll
    for (int off = 1; off < 64; off <<= 1)
        v = min(v, __shfl_xor(v, off));
    return v;
}

// 4-wave LDS-counter barrier (wv4 excluded), sleepy spin
__device__ __forceinline__ void bar4(int* cnt, int target){
    asm volatile("s_waitcnt lgkmcnt(0)" ::: "memory");
    if ((threadIdx.x & 63) == 0)
        __hip_atomic_fetch_add(cnt, 1, __ATOMIC_RELAXED, __HIP_MEMORY_SCOPE_WORKGROUP);
    while (__hip_atomic_load(cnt, __ATOMIC_RELAXED, __HIP_MEMORY_SCOPE_WORKGROUP) < target)
        __builtin_amdgcn_s_sleep(1);
    asm volatile("" ::: "memory");
}

// ---------------- GEMM helpers ----------------

__device__ __forceinline__ f32x4 mfma16(f16x8 a, f16x8 b, f32x4 c){
    return __builtin_amdgcn_mfma_f32_16x16x32_f16(a, b, c, 0, 0, 0);
}

// B from frag-ordered LDS: wfrag = region base + lane*16; read at kk*1024.
__device__ __forceinline__ void gemm_half_ldsb(const _Float16* A, const char* wfrag,
                                               f32x4* acc){
    f16x8 a[32];
    #pragma unroll
    for (int kk = 0; kk < 8; ++kk)
        #pragma unroll
        for (int m = 0; m < 4; ++m)
            a[kk*4+m] = *reinterpret_cast<const f16x8*>(A + kk*32 + m*16*1024);
    #pragma unroll
    for (int kk = 0; kk < 8; ++kk){
        f16x8 bb = *reinterpret_cast<const f16x8*>(wfrag + kk*1024);
        acc[0] = mfma16(a[kk*4+0], bb, acc[0]);
        acc[1] = mfma16(a[kk*4+1], bb, acc[1]);
        acc[2] = mfma16(a[kk*4+2], bb, acc[2]);
        acc[3] = mfma16(a[kk*4+3], bb, acc[3]);
    }
    #pragma unroll
    for (int kk = 8; kk < 16; ++kk)
        #pragma unroll
        for (int m = 0; m < 4; ++m)
            a[(kk-8)*4+m] = *reinterpret_cast<const f16x8*>(A + kk*32 + m*16*1024);
    #pragma unroll
    for (int kk = 8; kk < 16; ++kk){
        f16x8 bb = *reinterpret_cast<const f16x8*>(wfrag + kk*1024);
        acc[0] = mfma16(a[(kk-8)*4+0], bb, acc[0]);
        acc[1] = mfma16(a[(kk-8)*4+1], bb, acc[1]);
        acc[2] = mfma16(a[(kk-8)*4+2], bb, acc[2]);
        acc[3] = mfma16(a[(kk-8)*4+3], bb, acc[3]);
    }
}

// B from global (x-weights, L2-resident)
__device__ __forceinline__ void gemm_half_gb(const _Float16* A, const _Float16* Wp,
                                             f32x4* acc){
    f16x8 a[32];
    #pragma unroll
    for (int kk = 0; kk < 8; ++kk)
        #pragma unroll
        for (int m = 0; m < 4; ++m)
            a[kk*4+m] = *reinterpret_cast<const f16x8*>(A + kk*32 + m*16*1024);
    #pragma unroll
    for (int kk = 0; kk < 8; ++kk){
        f16x8 bb = *reinterpret_cast<const f16x8*>(Wp + kk*32);
        acc[0] = mfma16(a[kk*4+0], bb, acc[0]);
        acc[1] = mfma16(a[kk*4+1], bb, acc[1]);
        acc[2] = mfma16(a[kk*4+2], bb, acc[2]);
        acc[3] = mfma16(a[kk*4+3], bb, acc[3]);
    }
    #pragma unroll
    for (int kk = 8; kk < 16; ++kk)
        #pragma unroll
        for (int m = 0; m < 4; ++m)
            a[(kk-8)*4+m] = *reinterpret_cast<const f16x8*>(A + kk*32 + m*16*1024);
    #pragma unroll
    for (int kk = 8; kk < 16; ++kk){
        f16x8 bb = *reinterpret_cast<const f16x8*>(Wp + kk*32);
        acc[0] = mfma16(a[(kk-8)*4+0], bb, acc[0]);
        acc[1] = mfma16(a[(kk-8)*4+1], bb, acc[1]);
        acc[2] = mfma16(a[(kk-8)*4+2], bb, acc[2]);
        acc[3] = mfma16(a[(kk-8)*4+3], bb, acc[3]);
    }
}

__device__ __forceinline__ void gemm_q_f32(const float* A, const _Float16* Wp, f32x4* acc){
    #pragma unroll 2
    for (int kk = 0; kk < 16; ++kk){
        f16x8 b = *reinterpret_cast<const f16x8*>(Wp + kk*32);
        f16x8 a[4];
        #pragma unroll
        for (int m = 0; m < 4; ++m){
            float4 u0 = *reinterpret_cast<const float4*>(A + kk*32 + (size_t)m*16*1024);
            float4 u1 = *reinterpret_cast<const float4*>(A + kk*32 + (size_t)m*16*1024 + 4);
            f16x8 v;
            v[0]=(_Float16)u0.x; v[1]=(_Float16)u0.y; v[2]=(_Float16)u0.z; v[3]=(_Float16)u0.w;
            v[4]=(_Float16)u1.x; v[5]=(_Float16)u1.y; v[6]=(_Float16)u1.z; v[7]=(_Float16)u1.w;
            a[m] = v;
        }
        acc[0] = mfma16(a[0], b, acc[0]);
        acc[1] = mfma16(a[1], b, acc[1]);
        acc[2] = mfma16(a[2], b, acc[2]);
        acc[3] = mfma16(a[3], b, acc[3]);
    }
}

// ---------------- persistent LSTM kernel ----------------

__global__ __launch_bounds__(320, 1)
void lstm_persist(const _Float16* __restrict__ Wr0, const _Float16* __restrict__ Wr1,
                  const float* __restrict__ br0, const float* __restrict__ br1,
                  const _Float16* __restrict__ xbf, const float* __restrict__ xf32,
                  int use_xf16, const _Float16* __restrict__ hz,
                  _Float16* h0ring, _Float16* h1ring, float* out, int* flags){
    extern __shared__ char smem[];
    float (*accL)[4][64][17] = reinterpret_cast<float(*)[4][64][17]>(smem + 98304);
    int* barCnt = reinterpret_cast<int*>(smem + 133120);

    const int tid  = threadIdx.x;
    const int wg   = blockIdx.x;
    const int wv   = tid >> 6;            // 0..4 (wv4 = comms/exit)
    const int lane = tid & 63;
    const int r    = lane & 15;
    const int q    = lane >> 4;
    const int p0   = wg * 16;
    const int rep  = wg & 31;

    // stage recurrent-path weights, FRAG-ORDERED (conflict-free consumers)
    for (int idx = tid; idx < 6144; idx += 320){
        const _Float16* s; char* dst;
        if (idx < 2048){                     // Wh0: wvh = idx>>10, kk, ln
            int wvh = idx >> 10, kk = (idx >> 6) & 15, ln = idx & 63;
            s = Wr0 + (size_t)(p0 + (ln & 15))*KCAT + 1024 + wvh*512 + kk*32 + (ln >> 4)*8;
            dst = smem + idx*16;
        } else {                             // W1: d = idx-2048
            int d = idx - 2048;
            int wvd = d >> 10, kk = (d >> 6) & 15, ln = d & 63;
            s = Wr1 + (size_t)(p0 + (ln & 15))*KCAT + wvd*512 + kk*32 + (ln >> 4)*8;
            dst = smem + 32768 + d*16;
        }
        *reinterpret_cast<f16x8*>(dst) = *reinterpret_cast<const f16x8*>(s);
    }
    if (tid == 0) *barCnt = 0;
    __syncthreads();   // all 5 waves; last time wv4 barriers

    // ================= comms wave =================
    if (wv == 4){
        if (wg == 0){
            int e0 = 0, e1 = 0;
            for(;;){
                int f0 = 0x7fffffff, f1 = 0x7fffffff;
                #pragma unroll
                for (int j = 0; j < 4; ++j){
                    int i4 = lane*4 + j;
                    f0 = min(f0, gload(&flags[F0_BASE + i4*32]));
                    f1 = min(f1, gload(&flags[F1_BASE + i4*32]));
                }
                int g0 = wave_min(f0), g1 = wave_min(f1);
                if (g0 > e0){
                    if (lane < 32) gstore(&flags[E0_IDX + lane*32], g0);
                    e0 = g0;
                }
                if (g1 > e1){
                    if (lane < 32) gstore(&flags[E1_IDX + lane*32], g1);
                    e1 = g1;
                }
                if (e1 >= SEQ) break;
                __builtin_amdgcn_s_sleep(1);
            }
        }
        return;
    }

    // ================= compute waves (wv0-3) =================
    f32x4 cst = {0.f,0.f,0.f,0.f};
    f32x4 ho_keep = {0.f,0.f,0.f,0.f};
    f32x4 bias[4];
    {
        const float* bsrc = (wv == 0) ? br0 : br1;
        #pragma unroll
        for (int jj = 0; jj < 4; ++jj)
            bias[jj] = *reinterpret_cast<const f32x4*>(&bsrc[p0 + jj*4]);
    }

    const int kofs = (wv & 1)*512 + q*8;
    const int wcol = wv*512 + q*8;
    const char* wh0frag = smem + (wv >= 2 ? (wv-2)*16384 : 0) + lane*16;
    const char* w1frag  = smem + 32768 + wv*16384 + lane*16;
    const size_t BH = (size_t)BATCH*HID;
    int btgt = 4;

    for (int k = 0; k <= SEQ; ++k){
        // ---------------- PHASE 1 ----------------
        f32x4 acc[4];
        #pragma unroll
        for (int m = 0; m < 4; ++m){ acc[m].x=0;acc[m].y=0;acc[m].z=0;acc[m].w=0; }

        if (wv < 2){
            if (k < SEQ){
                if (use_xf16)
                    gemm_half_gb(xbf + (size_t)k*BH + (size_t)r*HID + kofs,
                                 Wr0 + (size_t)(p0 + r)*KCAT + wcol, acc);
                else
                    gemm_q_f32(xf32 + (size_t)k*BH + (size_t)r*HID + kofs,
                               Wr0 + (size_t)(p0 + r)*KCAT + wcol, acc);
            }
        } else {
            if (k > 0) wait_epoch_g(flags, E0_IDX, k, rep);
            if (k < SEQ){
                const _Float16* A0 = (k == 0) ? (hz + (size_t)r*HID + kofs)
                                              : (h0ring + (size_t)(k-1)*BH + (size_t)r*HID + kofs);
                gemm_half_ldsb(A0, wh0frag, acc);
            }
        }

        #pragma unroll
        for (int mt = 0; mt < 4; ++mt)
            #pragma unroll
            for (int j = 0; j < 4; ++j)
                accL[0][wv][mt*16 + q*4 + j][r] = acc[mt][j];
        bar4(barCnt, btgt); btgt += 4;   // SYNC_A

        if (wv == 0 && k < SEQ){
            f32x4 zz[4];
            #pragma unroll
            for (int jj = 0; jj < 4; ++jj) zz[jj] = bias[jj];
            #pragma unroll
            for (int w2 = 0; w2 < 4; ++w2)
                #pragma unroll
                for (int jj = 0; jj < 4; ++jj){
                    f32x4 a = *reinterpret_cast<const f32x4*>(&accL[0][w2][lane][jj*4]);
                    zz[jj].x += a.x; zz[jj].y += a.y; zz[jj].z += a.z; zz[jj].w += a.w;
                }
            f16x4 hv;
            #pragma unroll
            for (int jl = 0; jl < 4; ++jl){
                float ig = sigm_f(zz[jl].x), fg = sigm_f(zz[jl].y);
                float gg = tanh_f(zz[jl].z), og = sigm_f(zz[jl].w);
                float c = fg*cst[jl] + ig*gg;  cst[jl] = c;
                hv[jl] = (_Float16)(og * tanh_f(c));
            }
            store_h8(h0ring + ((size_t)k*BATCH + lane)*HID + wg*4, hv);
            drain_vmem();
            if (lane == 0) gstore(&flags[F0_BASE + wg*32], k + 1);
        }

        // ---------------- PHASE 2 ----------------
        #pragma unroll
        for (int m = 0; m < 4; ++m){ acc[m].x=0;acc[m].y=0;acc[m].z=0;acc[m].w=0; }

        if (k >= 1){
            if (wv < 2){
                // SYNC_A implies epoch0 >= k (wv2/3 observed it) -> no wait
                gemm_half_ldsb(h0ring + (size_t)(k-1)*BH + (size_t)r*HID + kofs,
                               w1frag, acc);
            } else {
                if (k >= 2) wait_epoch_g(flags, E1_IDX, k-1, rep);
                const _Float16* A1 = (k == 1) ? (hz + (size_t)r*HID + kofs)
                                              : (h1ring + (size_t)(k-2)*BH + (size_t)r*HID + kofs);
                gemm_half_ldsb(A1, w1frag, acc);
            }
        }

        #pragma unroll
        for (int mt = 0; mt < 4; ++mt)
            #pragma unroll
            for (int j = 0; j < 4; ++j)
                accL[1][wv][mt*16 + q*4 + j][r] = acc[mt][j];
        bar4(barCnt, btgt); btgt += 4;   // SYNC_B

        if (wv == 1 && k >= 1){
            const int t1 = k - 1;
            f32x4 zz[4];
            #pragma unroll
            for (int jj = 0; jj < 4; ++jj) zz[jj] = bias[jj];
            #pragma unroll
            for (int w2 = 0; w2 < 4; ++w2)
                #pragma unroll
                for (int jj = 0; jj < 4; ++jj){
                    f32x4 a = *reinterpret_cast<const f32x4*>(&accL[1][w2][lane][jj*4]);
                    zz[jj].x += a.x; zz[jj].y += a.y; zz[jj].z += a.z; zz[jj].w += a.w;
                }
            f16x4 hv; f32x4 ho;
            #pragma unroll
            for (int jl = 0; jl < 4; ++jl){
                float ig = sigm_f(zz[jl].x), fg = sigm_f(zz[jl].y);
                float gg = tanh_f(zz[jl].z), og = sigm_f(zz[jl].w);
                float c = fg*cst[jl] + ig*gg;  cst[jl] = c;
                float h = og * tanh_f(c);
                hv[jl] = (_Float16)h;  ho[jl] = h;
            }
            if (k < SEQ) store_h8(h1ring + ((size_t)t1*BATCH + lane)*HID + wg*4, hv);
            if (t1 < SEQ-1) *reinterpret_cast<f32x4*>(out + ((size_t)t1*BATCH + lane)*HID + wg*4) = ho;
            else            ho_keep = ho;   // out[511] deferred (alias safety)
            drain_vmem();
            if (lane == 0) gstore(&flags[F1_BASE + wg*32], k);
        }
    }

    // epilogue: all wgs' phase-2 reads of h0[511] done once epoch1 >= SEQ
    if (wv == 1){
        wait_epoch_g(flags, E1_IDX, SEQ, rep);
        *reinterpret_cast<f32x4*>(out + ((size_t)(SEQ-1)*BATCH + lane)*HID + wg*4) = ho_keep;
    }
}

// ---------------- host launcher ----------------

extern "C" void kernel_launch(void* const* d_in, const int* in_sizes, int n_in,
                              void* d_out, int out_size, void* d_ws, size_t ws_size,
                              hipStream_t stream){
    const float* x   = (const float*)d_in[0];
    const float* Wx0 = (const float*)d_in[1];
    const float* bx0 = (const float*)d_in[2];
    const float* Wh0 = (const float*)d_in[3];
    const float* bh0 = (const float*)d_in[4];
    const float* Wx1 = (const float*)d_in[5];
    const float* bx1 = (const float*)d_in[6];
    const float* Wh1 = (const float*)d_in[7];
    const float* bh1 = (const float*)d_in[8];
    float* out = (float*)d_out;
    char* ws = (char*)d_ws;

    size_t o = 0;
    _Float16* Wr0 = (_Float16*)(ws + o); o += (size_t)NG*KCAT*2;
    _Float16* Wr1 = (_Float16*)(ws + o); o += (size_t)NG*KCAT*2;
    float* br0 = (float*)(ws + o); o += 16384;
    float* br1 = (float*)(ws + o); o += 16384;
    _Float16* h1ring = (_Float16*)(ws + o); o += (size_t)SEQ*BATCH*HID*2;
    _Float16* hz     = (_Float16*)(ws + o); o += (size_t)BATCH*HID*2;
    int* flags = (int*)(ws + o); o += 131072;

    const size_t RING = (size_t)SEQ*BATCH*HID*2;
    _Float16 *xbf = nullptr, *h0ring;
    int use_xf16 = 0;
    if (ws_size >= o + 2*RING){
        xbf    = (_Float16*)(ws + o);  o += RING;  use_xf16 = 1;
        h0ring = (_Float16*)(ws + o);  o += RING;
    } else if (ws_size >= o + RING){
        xbf    = (_Float16*)(ws + o);  o += RING;  use_xf16 = 1;
        h0ring = (_Float16*)((char*)d_out + (size_t)64*1024*1024);
    } else {
        h0ring = (_Float16*)((char*)d_out + (size_t)64*1024*1024);
    }

    hipFuncSetAttribute((const void*)lstm_persist,
                        hipFuncAttributeMaxDynamicSharedMemorySize, SMEM_BYTES);

    prep_w_kernel<<<NG, 256, 0, stream>>>(Wx0, Wh0, bx0, bh0, Wr0, br0);
    prep_w_kernel<<<NG, 256, 0, stream>>>(Wx1, Wh1, bx1, bh1, Wr1, br1);
    if (use_xf16)
        prep_x_kernel<<<(SEQ*BATCH*HID)/(256*8), 256, 0, stream>>>(x, xbf);
    init_misc_kernel<<<128, 256, 0, stream>>>(flags, hz);
    lstm_persist<<<256, 320, SMEM_BYTES, stream>>>(Wr0, Wr1, br0, br1, xbf, x, use_xf16,
                                                   hz, h0ring, h1ring, out, flags);
}

// Round 14
// 8758.344 us; speedup vs baseline: 1.3317x; 1.3317x over previous
//
#include <hip/hip_runtime.h>

// LSTM 2-layer, S=512 B=64 IN=H=1024, fp32 I/O, fp16 MFMA compute.
// R14 = R13 with the asm-MLP GEMMs made SAFE (R13 NaN post-mortem):
//   - flight capped at 32 loads/bank (peak ~160 VGPR of asm outputs; R13's
//     80-deep version needed 320 VGPR -> spill of in-flight load dests =
//     garbage + vmcnt contamination);
//   - only s_waitcnt vmcnt(0) (count-free; counted vmcnt(32) breaks if ANY
//     compiler VMEM lands in the region);
//   - sched_barrier(0) fences each bank (no compiler code enters region,
//     no MFMA hoisted above the wait — guide rule #18).
// Per GEMM: 2 banks x {32 ordered asm global_load_dwordx4 -> vmcnt(0) ->
// 32 MFMA (B from frag-ordered LDS / global)}.
// Rest identical to R13 (= R9 skeleton + frag-ordered weight LDS):
// two-phase round, split epoch chains, top-of-phase aggregation by wg0,
// sc0|sc1 h rings, relaxed flags, no fences in loop, h0ring may alias
// d_out upper half (out[511] deferred past final epoch).

#define SEQ   512
#define BATCH 64
#define HID   1024
#define NG    4096
#define KCAT  2048
#define F0_BASE 0            // flags0: + wg*32
#define E0_IDX  8192         // epoch0 replicas: + (wg&31)*32
#define F1_BASE 16384        // flags1: + wg*32
#define E1_IDX  24576        // epoch1 replicas: + (wg&31)*32

// dynamic LDS (bytes):
//   [0,32768)       Wh0 frag-ordered: (wvh,kk,lane) -> wvh*16384+kk*1024+lane*16
//   [32768,98304)   W1  frag-ordered: (wv,kk,lane)  -> 32768+wv*16384+kk*1024+lane*16
//   [98304,133120)  accL: float[2][4][64][17]
#define SMEM_BYTES 133120

typedef __attribute__((ext_vector_type(8))) _Float16 f16x8;
typedef __attribute__((ext_vector_type(4))) _Float16 f16x4;
typedef __attribute__((ext_vector_type(4))) float    f32x4;

__device__ __forceinline__ float sigm_f(float x){ return 1.f/(1.f + __expf(-x)); }
__device__ __forceinline__ float tanh_f(float x){
    float e = __expf(-2.f*fabsf(x));
    float r = (1.f - e)/(1.f + e);
    return copysignf(r, x);
}

__device__ __forceinline__ void store_h8(_Float16* p, f16x4 v){
    asm volatile("global_store_dwordx2 %0, %1, off sc0 sc1" :: "v"(p), "v"(v) : "memory");
}
__device__ __forceinline__ void drain_vmem(){
    asm volatile("s_waitcnt vmcnt(0)" ::: "memory");
}

// ---- ordered asm loads ----
#define GLD(dst, base, OFF) \
    asm volatile("global_load_dwordx4 %0, %1, off offset:" #OFF \
                 : "=&v"(dst) : "v"(base))
#define GLD8L(arr, i, B) \
    GLD(arr[(i)+0],B,0);   GLD(arr[(i)+1],B,64);  GLD(arr[(i)+2],B,128); GLD(arr[(i)+3],B,192); \
    GLD(arr[(i)+4],B,256); GLD(arr[(i)+5],B,320); GLD(arr[(i)+6],B,384); GLD(arr[(i)+7],B,448)
#define GLD8H(arr, i, B) \
    GLD(arr[(i)+0],B,512); GLD(arr[(i)+1],B,576); GLD(arr[(i)+2],B,640); GLD(arr[(i)+3],B,704); \
    GLD(arr[(i)+4],B,768); GLD(arr[(i)+5],B,832); GLD(arr[(i)+6],B,896); GLD(arr[(i)+7],B,960)
#define VMWAIT0 \
    asm volatile("s_waitcnt vmcnt(0)" ::: "memory"); \
    __builtin_amdgcn_sched_barrier(0)

// ---------------- prep kernels ----------------

__global__ void prep_w_kernel(const float* __restrict__ Wx, const float* __restrict__ Wh,
                              const float* __restrict__ bx, const float* __restrict__ bh,
                              _Float16* __restrict__ Wr, float* __restrict__ br){
    int p = blockIdx.x;
    int j = p >> 2, g = p & 3;
    int r = g*1024 + j;
    int k = threadIdx.x * 8;
    const float* s = (k < 1024) ? (Wx + (size_t)r*1024 + k)
                                : (Wh + (size_t)r*1024 + (k - 1024));
    float4 v0 = *reinterpret_cast<const float4*>(s);
    float4 v1 = *reinterpret_cast<const float4*>(s + 4);
    f16x8 o;
    o[0]=(_Float16)v0.x; o[1]=(_Float16)v0.y; o[2]=(_Float16)v0.z; o[3]=(_Float16)v0.w;
    o[4]=(_Float16)v1.x; o[5]=(_Float16)v1.y; o[6]=(_Float16)v1.z; o[7]=(_Float16)v1.w;
    *reinterpret_cast<f16x8*>(Wr + (size_t)p*KCAT + k) = o;
    if (threadIdx.x == 0) br[p] = bx[r] + bh[r];
}

__global__ void prep_x_kernel(const float* __restrict__ x, _Float16* xo){
    size_t i = ((size_t)blockIdx.x*256 + threadIdx.x) * 8;
    float4 v0 = *reinterpret_cast<const float4*>(x + i);
    float4 v1 = *reinterpret_cast<const float4*>(x + i + 4);
    f16x8 o;
    o[0]=(_Float16)v0.x; o[1]=(_Float16)v0.y; o[2]=(_Float16)v0.z; o[3]=(_Float16)v0.w;
    o[4]=(_Float16)v1.x; o[5]=(_Float16)v1.y; o[6]=(_Float16)v1.z; o[7]=(_Float16)v1.w;
    *reinterpret_cast<f16x8*>(xo + i) = o;
}

__global__ void init_misc_kernel(int* flags, _Float16* hz){
    int i = blockIdx.x*256 + threadIdx.x;            // 32768 threads
    flags[i] = 0;
    if (i < 16384){
        f16x4 z; z[0]=(_Float16)0.f; z[1]=(_Float16)0.f; z[2]=(_Float16)0.f; z[3]=(_Float16)0.f;
        *reinterpret_cast<f16x4*>(hz + (size_t)i*4) = z;
    }
}

// ---------------- sync helpers (no fences) ----------------

__device__ __forceinline__ void wait_epoch_g(const int* flags, int eidx, int k, int rep){
    for(;;){
        int e = __hip_atomic_load(&flags[eidx + rep*32], __ATOMIC_RELAXED, __HIP_MEMORY_SCOPE_AGENT);
        if (e >= k) break;
        __builtin_amdgcn_s_sleep(2);
    }
    asm volatile("" ::: "memory");
}

__device__ __forceinline__ void aggregate_publish(int* flags, int base, int eidx,
                                                  int k, int lane){
    const int b = lane*4;
    for(;;){
        int a0 = __hip_atomic_load(&flags[base + (b+0)*32], __ATOMIC_RELAXED, __HIP_MEMORY_SCOPE_AGENT);
        int a1 = __hip_atomic_load(&flags[base + (b+1)*32], __ATOMIC_RELAXED, __HIP_MEMORY_SCOPE_AGENT);
        int a2 = __hip_atomic_load(&flags[base + (b+2)*32], __ATOMIC_RELAXED, __HIP_MEMORY_SCOPE_AGENT);
        int a3 = __hip_atomic_load(&flags[base + (b+3)*32], __ATOMIC_RELAXED, __HIP_MEMORY_SCOPE_AGENT);
        bool ok = (a0>=k) && (a1>=k) && (a2>=k) && (a3>=k);
        if (__all(ok)) break;
        __builtin_amdgcn_s_sleep(1);
    }
    asm volatile("" ::: "memory");
    if (lane < 32)
        __hip_atomic_store(&flags[eidx + lane*32], k, __ATOMIC_RELAXED, __HIP_MEMORY_SCOPE_AGENT);
}

// ---------------- GEMM helpers ----------------

__device__ __forceinline__ f32x4 mfma16(f16x8 a, f16x8 b, f32x4 c){
    return __builtin_amdgcn_mfma_f32_16x16x32_f16(a, b, c, 0, 0, 0);
}

// A via asm loads, 32-flight banks, vmcnt(0) only; B from frag-ordered LDS.
__device__ __forceinline__ void gemm_asm_ldsb(const _Float16* A, const char* wfrag,
                                              f32x4* acc){
    const _Float16* b0 = A;
    const _Float16* b1 = A + 16*1024;
    const _Float16* b2 = A + 32*1024;
    const _Float16* b3 = A + 48*1024;
    f16x8 a[32];
    __builtin_amdgcn_sched_barrier(0);
    GLD8L(a, 0, b0); GLD8L(a, 8, b1); GLD8L(a, 16, b2); GLD8L(a, 24, b3);   // kk 0..7
    VMWAIT0;
    #pragma unroll
    for (int kk = 0; kk < 8; ++kk){
        f16x8 bb = *reinterpret_cast<const f16x8*>(wfrag + kk*1024);
        acc[0] = mfma16(a[kk],      bb, acc[0]);
        acc[1] = mfma16(a[8 + kk],  bb, acc[1]);
        acc[2] = mfma16(a[16 + kk], bb, acc[2]);
        acc[3] = mfma16(a[24 + kk], bb, acc[3]);
    }
    __builtin_amdgcn_sched_barrier(0);
    GLD8H(a, 0, b0); GLD8H(a, 8, b1); GLD8H(a, 16, b2); GLD8H(a, 24, b3);   // kk 8..15
    VMWAIT0;
    #pragma unroll
    for (int kk = 0; kk < 8; ++kk){
        f16x8 bb = *reinterpret_cast<const f16x8*>(wfrag + (8 + kk)*1024);
        acc[0] = mfma16(a[kk],      bb, acc[0]);
        acc[1] = mfma16(a[8 + kk],  bb, acc[1]);
        acc[2] = mfma16(a[16 + kk], bb, acc[2]);
        acc[3] = mfma16(a[24 + kk], bb, acc[3]);
    }
    __builtin_amdgcn_sched_barrier(0);
}

// A + B via asm loads (B from global, L2-resident x-weights), same banking.
__device__ __forceinline__ void gemm_asm_gb(const _Float16* A, const _Float16* Wp,
                                            f32x4* acc){
    const _Float16* b0 = A;
    const _Float16* b1 = A + 16*1024;
    const _Float16* b2 = A + 32*1024;
    const _Float16* b3 = A + 48*1024;
    f16x8 bw[8], a[32];
    __builtin_amdgcn_sched_barrier(0);
    GLD8L(bw, 0, Wp);                                                        // B kk 0..7
    GLD8L(a, 0, b0); GLD8L(a, 8, b1); GLD8L(a, 16, b2); GLD8L(a, 24, b3);    // A kk 0..7
    VMWAIT0;
    #pragma unroll
    for (int kk = 0; kk < 8; ++kk){
        acc[0] = mfma16(a[kk],      bw[kk], acc[0]);
        acc[1] = mfma16(a[8 + kk],  bw[kk], acc[1]);
        acc[2] = mfma16(a[16 + kk], bw[kk], acc[2]);
        acc[3] = mfma16(a[24 + kk], bw[kk], acc[3]);
    }
    __builtin_amdgcn_sched_barrier(0);
    GLD8H(bw, 0, Wp);                                                        // B kk 8..15
    GLD8H(a, 0, b0); GLD8H(a, 8, b1); GLD8H(a, 16, b2); GLD8H(a, 24, b3);    // A kk 8..15
    VMWAIT0;
    #pragma unroll
    for (int kk = 0; kk < 8; ++kk){
        acc[0] = mfma16(a[kk],      bw[kk], acc[0]);
        acc[1] = mfma16(a[8 + kk],  bw[kk], acc[1]);
        acc[2] = mfma16(a[16 + kk], bw[kk], acc[2]);
        acc[3] = mfma16(a[24 + kk], bw[kk], acc[3]);
    }
    __builtin_amdgcn_sched_barrier(0);
}

// f32 x fallback (only when ws too small for xbf)
__device__ __forceinline__ void gemm_q_f32(const float* A, const _Float16* Wp, f32x4* acc){
    #pragma unroll 2
    for (int kk = 0; kk < 16; ++kk){
        f16x8 b = *reinterpret_cast<const f16x8*>(Wp + kk*32);
        f16x8 a[4];
        #pragma unroll
        for (int m = 0; m < 4; ++m){
            float4 u0 = *reinterpret_cast<const float4*>(A + kk*32 + (size_t)m*16*1024);
            float4 u1 = *reinterpret_cast<const float4*>(A + kk*32 + (size_t)m*16*1024 + 4);
            f16x8 v;
            v[0]=(_Float16)u0.x; v[1]=(_Float16)u0.y; v[2]=(_Float16)u0.z; v[3]=(_Float16)u0.w;
            v[4]=(_Float16)u1.x; v[5]=(_Float16)u1.y; v[6]=(_Float16)u1.z; v[7]=(_Float16)u1.w;
            a[m] = v;
        }
        acc[0] = mfma16(a[0], b, acc[0]);
        acc[1] = mfma16(a[1], b, acc[1]);
        acc[2] = mfma16(a[2], b, acc[2]);
        acc[3] = mfma16(a[3], b, acc[3]);
    }
}

// ---------------- persistent LSTM kernel ----------------

__global__ __launch_bounds__(256, 1)
void lstm_persist(const _Float16* __restrict__ Wr0, const _Float16* __restrict__ Wr1,
                  const float* __restrict__ br0, const float* __restrict__ br1,
                  const _Float16* __restrict__ xbf, const float* __restrict__ xf32,
                  int use_xf16, const _Float16* __restrict__ hz,
                  _Float16* h0ring, _Float16* h1ring, float* out, int* flags){
    extern __shared__ char smem[];
    float (*accL)[4][64][17] = reinterpret_cast<float(*)[4][64][17]>(smem + 98304);

    const int tid  = threadIdx.x;
    const int wg   = blockIdx.x;
    const int wv   = tid >> 6;
    const int lane = tid & 63;
    const int r    = lane & 15;
    const int q    = lane >> 4;
    const int p0   = wg * 16;
    const int rep  = wg & 31;

    // stage recurrent-path weights, FRAG-ORDERED
    for (int idx = tid; idx < 6144; idx += 256){
        const _Float16* s; char* dst;
        if (idx < 2048){                     // Wh0
            int wvh = idx >> 10, kk = (idx >> 6) & 15, ln = idx & 63;
            s = Wr0 + (size_t)(p0 + (ln & 15))*KCAT + 1024 + wvh*512 + kk*32 + (ln >> 4)*8;
            dst = smem + idx*16;
        } else {                             // W1
            int d = idx - 2048;
            int wvd = d >> 10, kk = (d >> 6) & 15, ln = d & 63;
            s = Wr1 + (size_t)(p0 + (ln & 15))*KCAT + wvd*512 + kk*32 + (ln >> 4)*8;
            dst = smem + 32768 + d*16;
        }
        *reinterpret_cast<f16x8*>(dst) = *reinterpret_cast<const f16x8*>(s);
    }
    __syncthreads();

    f32x4 cst = {0.f,0.f,0.f,0.f};
    f32x4 ho_keep = {0.f,0.f,0.f,0.f};
    f32x4 bias[4];
    {
        const float* bsrc = (wv == 0) ? br0 : br1;
        #pragma unroll
        for (int jj = 0; jj < 4; ++jj)
            bias[jj] = *reinterpret_cast<const f32x4*>(&bsrc[p0 + jj*4]);
    }

    const int kofs = (wv & 1)*512 + q*8;
    const int wcol = wv*512 + q*8;
    const char* wh0frag = smem + (wv >= 2 ? (wv-2)*16384 : 0) + lane*16;
    const char* w1frag  = smem + 32768 + wv*16384 + lane*16;
    const size_t BH = (size_t)BATCH*HID;

    for (int k = 0; k <= SEQ; ++k){
        // ---------------- PHASE 1 ----------------
        f32x4 acc[4];
        #pragma unroll
        for (int m = 0; m < 4; ++m){ acc[m].x=0;acc[m].y=0;acc[m].z=0;acc[m].w=0; }

        if (wv < 2){
            if (k < SEQ){
                if (use_xf16)
                    gemm_asm_gb(xbf + (size_t)k*BH + (size_t)r*HID + kofs,
                                Wr0 + (size_t)(p0 + r)*KCAT + wcol, acc);
                else
                    gemm_q_f32(xf32 + (size_t)k*BH + (size_t)r*HID + kofs,
                               Wr0 + (size_t)(p0 + r)*KCAT + wcol, acc);
            }
        } else {
            if (k > 0){
                if (wg == 0 && wv == 3) aggregate_publish(flags, F0_BASE, E0_IDX, k, lane);
                else                    wait_epoch_g(flags, E0_IDX, k, rep);
            }
            if (k < SEQ){
                const _Float16* A0 = (k == 0) ? (hz + (size_t)r*HID + kofs)
                                              : (h0ring + (size_t)(k-1)*BH + (size_t)r*HID + kofs);
                gemm_asm_ldsb(A0, wh0frag, acc);
            }
        }

        #pragma unroll
        for (int mt = 0; mt < 4; ++mt)
            #pragma unroll
            for (int j = 0; j < 4; ++j)
                accL[0][wv][mt*16 + q*4 + j][r] = acc[mt][j];
        __syncthreads();   // SYNC_A

        if (wv == 0 && k < SEQ){
            f32x4 zz[4];
            #pragma unroll
            for (int jj = 0; jj < 4; ++jj) zz[jj] = bias[jj];
            #pragma unroll
            for (int w2 = 0; w2 < 4; ++w2)
                #pragma unroll
                for (int jj = 0; jj < 4; ++jj){
                    f32x4 a = *reinterpret_cast<const f32x4*>(&accL[0][w2][lane][jj*4]);
                    zz[jj].x += a.x; zz[jj].y += a.y; zz[jj].z += a.z; zz[jj].w += a.w;
                }
            f16x4 hv;
            #pragma unroll
            for (int jl = 0; jl < 4; ++jl){
                float ig = sigm_f(zz[jl].x), fg = sigm_f(zz[jl].y);
                float gg = tanh_f(zz[jl].z), og = sigm_f(zz[jl].w);
                float c = fg*cst[jl] + ig*gg;  cst[jl] = c;
                hv[jl] = (_Float16)(og * tanh_f(c));
            }
            store_h8(h0ring + ((size_t)k*BATCH + lane)*HID + wg*4, hv);
            drain_vmem();
            if (lane == 0)
                __hip_atomic_store(&flags[F0_BASE + wg*32], k + 1,
                                   __ATOMIC_RELAXED, __HIP_MEMORY_SCOPE_AGENT);
        }

        // ---------------- PHASE 2 ----------------
        #pragma unroll
        for (int m = 0; m < 4; ++m){ acc[m].x=0;acc[m].y=0;acc[m].z=0;acc[m].w=0; }

        if (k >= 1){
            if (wv < 2){
                // SYNC_A implies epoch0 >= k (wv2/3 observed it) -> no wait
                gemm_asm_ldsb(h0ring + (size_t)(k-1)*BH + (size_t)r*HID + kofs,
                              w1frag, acc);
            } else {
                if (k >= 2){
                    if (wg == 0 && wv == 2) aggregate_publish(flags, F1_BASE, E1_IDX, k-1, lane);
                    else                    wait_epoch_g(flags, E1_IDX, k-1, rep);
                }
                const _Float16* A1 = (k == 1) ? (hz + (size_t)r*HID + kofs)
                                              : (h1ring + (size_t)(k-2)*BH + (size_t)r*HID + kofs);
                gemm_asm_ldsb(A1, w1frag, acc);
            }
        }

        #pragma unroll
        for (int mt = 0; mt < 4; ++mt)
            #pragma unroll
            for (int j = 0; j < 4; ++j)
                accL[1][wv][mt*16 + q*4 + j][r] = acc[mt][j];
        __syncthreads();   // SYNC_B

        if (wv == 1 && k >= 1){
            const int t1 = k - 1;
            f32x4 zz[4];
            #pragma unroll
            for (int jj = 0; jj < 4; ++jj) zz[jj] = bias[jj];
            #pragma unroll
            for (int w2 = 0; w2 < 4; ++w2)
                #pragma unroll
                for (int jj = 0; jj < 4; ++jj){
                    f32x4 a = *reinterpret_cast<const f32x4*>(&accL[1][w2][lane][jj*4]);
                    zz[jj].x += a.x; zz[jj].y += a.y; zz[jj].z += a.z; zz[jj].w += a.w;
                }
            f16x4 hv; f32x4 ho;
            #pragma unroll
            for (int jl = 0; jl < 4; ++jl){
                float ig = sigm_f(zz[jl].x), fg = sigm_f(zz[jl].y);
                float gg = tanh_f(zz[jl].z), og = sigm_f(zz[jl].w);
                float c = fg*cst[jl] + ig*gg;  cst[jl] = c;
                float h = og * tanh_f(c);
                hv[jl] = (_Float16)h;  ho[jl] = h;
            }
            if (k < SEQ) store_h8(h1ring + ((size_t)t1*BATCH + lane)*HID + wg*4, hv);
            if (t1 < SEQ-1) *reinterpret_cast<f32x4*>(out + ((size_t)t1*BATCH + lane)*HID + wg*4) = ho;
            else            ho_keep = ho;   // out[511] deferred (alias safety)
            drain_vmem();
            if (lane == 0)
                __hip_atomic_store(&flags[F1_BASE + wg*32], k,
                                   __ATOMIC_RELAXED, __HIP_MEMORY_SCOPE_AGENT);
        }
    }

    // epilogue (R9-verified): flag0=SEQ+1 after all local reads of h0[511]
    if (tid == 0)
        __hip_atomic_store(&flags[F0_BASE + wg*32], SEQ + 1,
                           __ATOMIC_RELAXED, __HIP_MEMORY_SCOPE_AGENT);
    if (wg == 0 && wv == 3) aggregate_publish(flags, F0_BASE, E0_IDX, SEQ + 1, lane);
    if (wv == 1){
        wait_epoch_g(flags, E0_IDX, SEQ + 1, rep);
        *reinterpret_cast<f32x4*>(out + ((size_t)(SEQ-1)*BATCH + lane)*HID + wg*4) = ho_keep;
    }
}

// ---------------- host launcher ----------------

extern "C" void kernel_launch(void* const* d_in, const int* in_sizes, int n_in,
                              void* d_out, int out_size, void* d_ws, size_t ws_size,
                              hipStream_t stream){
    const float* x   = (const float*)d_in[0];
    const float* Wx0 = (const float*)d_in[1];
    const float* bx0 = (const float*)d_in[2];
    const float* Wh0 = (const float*)d_in[3];
    const float* bh0 = (const float*)d_in[4];
    const float* Wx1 = (const float*)d_in[5];
    const float* bx1 = (const float*)d_in[6];
    const float* Wh1 = (const float*)d_in[7];
    const float* bh1 = (const float*)d_in[8];
    float* out = (float*)d_out;
    char* ws = (char*)d_ws;

    size_t o = 0;
    _Float16* Wr0 = (_Float16*)(ws + o); o += (size_t)NG*KCAT*2;
    _Float16* Wr1 = (_Float16*)(ws + o); o += (size_t)NG*KCAT*2;
    float* br0 = (float*)(ws + o); o += 16384;
    float* br1 = (float*)(ws + o); o += 16384;
    _Float16* h1ring = (_Float16*)(ws + o); o += (size_t)SEQ*BATCH*HID*2;
    _Float16* hz     = (_Float16*)(ws + o); o += (size_t)BATCH*HID*2;
    int* flags = (int*)(ws + o); o += 131072;

    const size_t RING = (size_t)SEQ*BATCH*HID*2;
    _Float16 *xbf = nullptr, *h0ring;
    int use_xf16 = 0;
    if (ws_size >= o + 2*RING){
        xbf    = (_Float16*)(ws + o);  o += RING;  use_xf16 = 1;
        h0ring = (_Float16*)(ws + o);  o += RING;
    } else if (ws_size >= o + RING){
        xbf    = (_Float16*)(ws + o);  o += RING;  use_xf16 = 1;
        h0ring = (_Float16*)((char*)d_out + (size_t)64*1024*1024);
    } else {
        h0ring = (_Float16*)((char*)d_out + (size_t)64*1024*1024);
    }

    hipFuncSetAttribute((const void*)lstm_persist,
                        hipFuncAttributeMaxDynamicSharedMemorySize, SMEM_BYTES);

    prep_w_kernel<<<NG, 256, 0, stream>>>(Wx0, Wh0, bx0, bh0, Wr0, br0);
    prep_w_kernel<<<NG, 256, 0, stream>>>(Wx1, Wh1, bx1, bh1, Wr1, br1);
    if (use_xf16)
        prep_x_kernel<<<(SEQ*BATCH*HID)/(256*8), 256, 0, stream>>>(x, xbf);
    init_misc_kernel<<<128, 256, 0, stream>>>(flags, hz);
    lstm_persist<<<256, 256, SMEM_BYTES, stream>>>(Wr0, Wr1, br0, br1, xbf, x, use_xf16,
                                                   hz, h0ring, h1ring, out, flags);
}